// Round 4
// baseline (792.141 us; speedup 1.0000x reference)
//
#include <hip/hip_runtime.h>
#include <hip/hip_bf16.h>
#include <stdint.h>

#define NN 50000
#define NE 800000
#define NR 16
#define NP (NN * NR)                 // 800000 (dst,rel) bins
#define NB1 ((NP + 255) / 256)       // 3125
#define TN 16                        // fused tile: 16 nodes (NN % 16 == 0 -> no tails)
#define NT16 (NN / TN)               // 3125 blocks

typedef unsigned short u16;
typedef unsigned int u32;
typedef unsigned char u8;

typedef __bf16 bf16x8 __attribute__((ext_vector_type(8)));
typedef __bf16 bf16x2 __attribute__((ext_vector_type(2)));
typedef float f32x4 __attribute__((ext_vector_type(4)));

__device__ __forceinline__ u16 f2bf(float f) {
  u32 u = __float_as_uint(f);
  u = u + 0x7FFFu + ((u >> 16) & 1u);
  return (u16)(u >> 16);
}

__device__ __forceinline__ u32 pk2bf(float x, float y) {
#if __has_builtin(__builtin_amdgcn_cvt_pk_bf16_f32)
  bf16x2 r = __builtin_amdgcn_cvt_pk_bf16_f32(x, y);
  union { bf16x2 v; u32 u; } c;
  c.v = r;
  return c.u;
#else
  return (u32)f2bf(x) | ((u32)f2bf(y) << 16);
#endif
}

__device__ __forceinline__ float bflo(u32 w) { return __uint_as_float(w << 16); }
__device__ __forceinline__ float bfhi(u32 w) { return __uint_as_float(w & 0xFFFF0000u); }

// ---------------- edge sort by (dst, rel) — counting sort over NP bins ----------------
// bin = dst*NR + rel: for a 4-node aligned group, ALL rels' edges are one contiguous
// range, sorted by (dst asc, rel asc) -> monotone 6-bit walk key ((dst&3)<<4)|rel.
__global__ void hist_kernel(const int* __restrict__ dst, const int* __restrict__ rel,
                            int* __restrict__ counts) {
  int e = blockIdx.x * 256 + threadIdx.x;
  if (e < NE) atomicAdd(&counts[dst[e] * NR + rel[e]], 1);
}

__global__ void scan_partial(const int* __restrict__ counts, int* __restrict__ bsum) {
  __shared__ int buf[256];
  int t = threadIdx.x;
  int i = blockIdx.x * 256 + t;
  int v = (i < NP) ? counts[i] : 0;
  buf[t] = v;
  __syncthreads();
  for (int off = 1; off < 256; off <<= 1) {
    int x = buf[t];
    int y = (t >= off) ? buf[t - off] : 0;
    __syncthreads();
    buf[t] = x + y;
    __syncthreads();
  }
  if (t == 255) bsum[blockIdx.x] = buf[255];
}

// single block, 1024 threads, 4-serial each: scans NB1 (<=4096) block sums
__global__ void scan_mid(const int* __restrict__ bsum, int* __restrict__ boff,
                         int* __restrict__ total_out) {
  __shared__ int buf[1024];
  int t = threadIdx.x;
  int v[4];
  int sum = 0;
#pragma unroll
  for (int i = 0; i < 4; ++i) {
    int idx = t * 4 + i;
    v[i] = (idx < NB1) ? bsum[idx] : 0;
    sum += v[i];
  }
  buf[t] = sum;
  __syncthreads();
  for (int off = 1; off < 1024; off <<= 1) {
    int x = buf[t];
    int y = (t >= off) ? buf[t - off] : 0;
    __syncthreads();
    buf[t] = x + y;
    __syncthreads();
  }
  int excl = buf[t] - sum;
#pragma unroll
  for (int i = 0; i < 4; ++i) {
    int idx = t * 4 + i;
    if (idx < NB1) { boff[idx] = excl; excl += v[i]; }
  }
  if (t == 1023) *total_out = buf[1023];
}

__global__ void scan_final(const int* __restrict__ counts, const int* __restrict__ boff,
                           int* __restrict__ starts, int* __restrict__ cursor) {
  __shared__ int buf[256];
  int t = threadIdx.x;
  int i = blockIdx.x * 256 + t;
  int v = (i < NP) ? counts[i] : 0;
  buf[t] = v;
  __syncthreads();
  for (int off = 1; off < 256; off <<= 1) {
    int x = buf[t];
    int y = (t >= off) ? buf[t - off] : 0;
    __syncthreads();
    buf[t] = x + y;
    __syncthreads();
  }
  int s = boff[blockIdx.x] + buf[t] - v;
  if (i < NP) {
    starts[i] = s;
    cursor[i] = s;
  }
}

// esd4[pos] = key6<<26 | src  (key6 = (dst&3)<<4 | rel, monotone within 4-node group)
__global__ void scatter_kernel(const int* __restrict__ src, const int* __restrict__ dst,
                               const int* __restrict__ rel, const float* __restrict__ norm,
                               int* __restrict__ cursor, u32* __restrict__ esd4,
                               u8* __restrict__ rels, float* __restrict__ norm_s) {
  int e = blockIdx.x * 256 + threadIdx.x;
  if (e < NE) {
    int d = dst[e];
    int r = rel[e];
    int pos = atomicAdd(&cursor[d * NR + r], 1);
    u32 key6 = ((u32)(d & 3) << 4) | (u32)r;
    esd4[pos] = (key6 << 26) | (u32)src[e];
    rels[pos] = (u8)r;
    norm_s[pos] = norm[e];
  }
}

// ---------------- weight convert: Wt[mat][d][k] = bf16(W[mat][k][d]) ----------------
// mats 0..15 = w0 rels, 16 = lw0, 17..32 = w1 rels, 33 = lw1
__global__ void convert_wt(const float* __restrict__ w0, const float* __restrict__ lw0,
                           const float* __restrict__ w1, const float* __restrict__ lw1,
                           u16* __restrict__ Wt) {
  int m = blockIdx.y;
  int idx = blockIdx.x * 256 + threadIdx.x; // 0..16383
  int d = idx >> 7, k = idx & 127;
  const float* s;
  if (m < 16) s = w0 + (size_t)m * 16384;
  else if (m == 16) s = lw0;
  else if (m < 33) s = w1 + (size_t)(m - 17) * 16384;
  else s = lw1;
  Wt[(size_t)m * 16384 + idx] = f2bf(s[k * 128 + d]);
}

// ---------------- h f32 -> bf16 (layer 0 input only) ----------------
__global__ void hconv_kernel(const float* __restrict__ h, u16* __restrict__ hbf) {
  int i = blockIdx.x * 256 + threadIdx.x; // float4 index
  float4 v = ((const float4*)h)[i];
  ushort4 u;
  u.x = f2bf(v.x); u.y = f2bf(v.y); u.z = f2bf(v.z); u.w = f2bf(v.w);
  ((ushort4*)hbf)[i] = u;
}

// ---------------- gate table: gates[r][n] = sigmoid(hbf[n] . gw[r]) ----------------
__global__ void gates_kernel(const u16* __restrict__ hbf, const float* __restrict__ gw,
                             float* __restrict__ gates) {
  __shared__ float hs[16 * 132];
  __shared__ float gws[16 * 132];
  int t = threadIdx.x;
  int n0 = blockIdx.x * 16;
#pragma unroll
  for (int i = 0; i < 2; ++i) {
    int f = t + 256 * i;            // 0..511
    int row = f >> 5, c4 = (f & 31) * 4;
    ushort4 u = *(const ushort4*)&hbf[(size_t)(n0 + row) * 128 + c4];
    hs[row * 132 + c4 + 0] = __uint_as_float((u32)u.x << 16);
    hs[row * 132 + c4 + 1] = __uint_as_float((u32)u.y << 16);
    hs[row * 132 + c4 + 2] = __uint_as_float((u32)u.z << 16);
    hs[row * 132 + c4 + 3] = __uint_as_float((u32)u.w << 16);
    *(float4*)&gws[row * 132 + c4] = *(const float4*)&gw[row * 128 + c4];
  }
  __syncthreads();
  int nl = t >> 4, r = t & 15;
  float s = 0.f;
#pragma unroll 8
  for (int k = 0; k < 128; ++k) s += hs[nl * 132 + k] * gws[r * 132 + k];
  gates[r * NN + n0 + nl] = 1.f / (1.f + __expf(-s));
}

// ---------------- per-edge coefficient: coef[e] = gate[rel][src] * norm ----------------
__global__ void coef_kernel(const u32* __restrict__ esd4, const u8* __restrict__ rels,
                            const float* __restrict__ norm_s,
                            const float* __restrict__ gates, float* __restrict__ coef) {
  int e = blockIdx.x * 256 + threadIdx.x;
  if (e < NE) {
    u32 sn = esd4[e] & 0xFFFFu;
    int r = rels[e];
    coef[e] = gates[(size_t)r * NN + sn] * norm_s[e];
  }
}

// ---------------- FUSED aggregate + GEMM, v4 ----------------
// Round-2 regression = scratch spill (lb(256,5) -> 51 VGPR vs ~90 live; WRITE 234MB).
// v4 structure: ONE aggregation pass + ONE barrier + one pure-MFMA section.
//  - (dst,rel) sort: each wave owns 4 nodes; its edges (all 16 rels) are ONE
//    contiguous range (~64 edges), walked with monotone key6=((dst&3)<<4)|rel.
//  - 2-deep ping-pong edge pipeline (meta B loads under gathers A).
//  - flush into 16 per-rel LDS tiles [16 rows x 256B], XOR-swizzled
//    (byte ^= (row&7)<<4): conflict-free ds_write (row-perm) and ds_read_b128.
//    Tiles pre-zeroed (16 ds_write_b128/wave); flush only nonempty bins.
//  - MFMA section: 17 mats, ping-pong weight frags fwA/fwB, self-loop operands
//    prefetched from global; no barriers inside.
//  - lb(256,2): VGPR cap 128 >= ~110 live -> NO spill. LDS 64KB -> 2 blocks/CU.
template <int LAYER>
__global__ __launch_bounds__(256, 2)
void fused_kernel(const u16* __restrict__ hbf, const u32* __restrict__ esd4,
                  const float* __restrict__ coef, const int* __restrict__ starts,
                  const u16* __restrict__ Wt, const float* __restrict__ bias,
                  u16* __restrict__ hb_out, float* __restrict__ fout) {
  __shared__ __align__(16) u16 As[16 * 16 * 128];   // 16 rel tiles x 16 rows x 256B
  const u32* hbf32 = (const u32*)hbf;
  int t = threadIdx.x;
  int n0 = blockIdx.x * TN;
  int wave = t >> 6;
  u32 lane = (u32)(t & 63);
  int wd = wave * 32;                // wave owns d rows [wd, wd+32)
  int mrow = t & 15, quad = (t & 63) >> 4;
  int vb = n0 + wave * 4;            // wave aggregates nodes [vb, vb+4)

  // ---- zero this wave's 4 rows in all 16 rel tiles (16 x ds_write_b128) ----
  {
    uint4 z = make_uint4(0, 0, 0, 0);
    u32 zrow = (u32)(wave * 4) + (lane >> 4);
    u32 zcol = (lane & 15u) * 16u;
#pragma unroll
    for (int r = 0; r < 16; ++r)
      *(uint4*)((char*)As + (u32)r * 4096u + zrow * 256u + zcol) = z;
  }

  // ---- aggregation: one contiguous edge range per wave ----
  int S = __builtin_amdgcn_readfirstlane(starts[vb * NR]);
  int E = __builtin_amdgcn_readfirstlane(starts[(vb + 4) * NR]); // starts[NP]=NE ok

  float a0 = 0.f, a1 = 0.f;
  int curk = -1;

#define LOADMETA(DS, CF, POS)                                                 \
  _Pragma("unroll")                                                           \
  for (int i = 0; i < 8; ++i) {                                               \
    DS[i] = esd4[(POS) + i];                                                  \
    CF[i] = coef[(POS) + i];                                                  \
  }

#define GATHER(W, DS)                                                         \
  _Pragma("unroll")                                                           \
  for (int i = 0; i < 8; ++i)                                                 \
    W[i] = hbf32[(DS[i] & 0xFFFFu) * 64u + lane];

#define FLUSHCUR()                                                            \
  {                                                                           \
    u32 frow = (u32)(wave * 4) + ((u32)curk >> 4);                            \
    u32 foff = ((u32)curk & 15u) * 4096u + frow * 256u +                      \
               ((lane * 4u) ^ ((frow & 7u) << 4));                            \
    *(u32*)((char*)As + foff) = pk2bf(a0, a1);                                \
  }

#define PROCESS(DS, CF, W, JB)                                                \
  _Pragma("unroll")                                                           \
  for (int i = 0; i < 8; ++i) {                                               \
    if ((JB) + i < E) {                                                       \
      int k = (int)(DS[i] >> 26);                                             \
      if (k != curk) {                                                        \
        if (curk >= 0) FLUSHCUR();                                            \
        a0 = 0.f; a1 = 0.f;                                                   \
        curk = k;                                                             \
      }                                                                       \
      float cfv = CF[i];                                                      \
      a0 = fmaf(cfv, bflo(W[i]), a0);                                         \
      a1 = fmaf(cfv, bfhi(W[i]), a1);                                         \
    }                                                                         \
  }

  {
    u32 dsA[8], dsB[8], wA[8], wB[8];
    float cfA[8], cfB[8];
    LOADMETA(dsA, cfA, S);
    for (int j = S; j < E; j += 16) {
      GATHER(wA, dsA);
      LOADMETA(dsB, cfB, j + 8);     // in flight under gather-A wait (pad covers OOB)
      PROCESS(dsA, cfA, wA, j);
      GATHER(wB, dsB);
      LOADMETA(dsA, cfA, j + 16);
      PROCESS(dsB, cfB, wB, j + 8);
    }
    if (curk >= 0) FLUSHCUR();
  }

  __syncthreads();                   // all tiles ready for all waves

  // ---- pure MFMA section: 17 mats, no barriers ----
  f32x4 acc[2];
  acc[0] = (f32x4){0.f, 0.f, 0.f, 0.f};
  acc[1] = (f32x4){0.f, 0.f, 0.f, 0.f};

  // self-loop A-operands (mat 16) prefetched from global (L2-hot)
  bf16x8 hself[4];
#pragma unroll
  for (int kk = 0; kk < 4; ++kk)
    hself[kk] = *(const bf16x8*)&hbf[(size_t)(n0 + mrow) * 128 + kk * 32 + quad * 8];

  bf16x8 fA[4][2], fB[4][2];

#define LOAD_FW(F, MAT)                                                       \
  {                                                                           \
    const u16* wmat = Wt + (size_t)(MAT) * 16384;                             \
    _Pragma("unroll")                                                         \
    for (int kk = 0; kk < 4; ++kk)                                            \
      _Pragma("unroll")                                                       \
      for (int i2 = 0; i2 < 2; ++i2)                                          \
        F[kk][i2] = *(const bf16x8*)&wmat[(wd + i2 * 16 + mrow) * 128 +       \
                                          kk * 32 + quad * 8];                \
  }

#define MFMA_TILE(F, MAT)                                                     \
  _Pragma("unroll")                                                           \
  for (int kk = 0; kk < 4; ++kk) {                                            \
    u32 off = (u32)(MAT) * 4096u + (u32)mrow * 256u +                         \
              (((u32)(kk * 64) + (u32)(quad * 16)) ^ ((u32)(mrow & 7) << 4)); \
    bf16x8 fb = *(const bf16x8*)((const char*)As + off);                      \
    acc[0] = __builtin_amdgcn_mfma_f32_16x16x32_bf16(F[kk][0], fb, acc[0],    \
                                                     0, 0, 0);                \
    acc[1] = __builtin_amdgcn_mfma_f32_16x16x32_bf16(F[kk][1], fb, acc[1],    \
                                                     0, 0, 0);                \
  }

  LOAD_FW(fA, 0);
#pragma unroll
  for (int m = 0; m < 16; m += 2) {
    LOAD_FW(fB, m + 1);
    MFMA_TILE(fA, m);
    LOAD_FW(fA, m + 2);              // m=14 -> mat 16 (self loop weights)
    MFMA_TILE(fB, m + 1);
  }
  // mat 16 = self loop: A-operand from registers (hself)
#pragma unroll
  for (int kk = 0; kk < 4; ++kk) {
    acc[0] = __builtin_amdgcn_mfma_f32_16x16x32_bf16(fA[kk][0], hself[kk],
                                                     acc[0], 0, 0, 0);
    acc[1] = __builtin_amdgcn_mfma_f32_16x16x32_bf16(fA[kk][1], hself[kk],
                                                     acc[1], 0, 0, 0);
  }

  // ---- epilogue: lane owns node n = n0 + mrow, d = wd + i2*16 + quad*4 .. +3 ----
  int n = n0 + mrow;                 // NN % 16 == 0 -> always valid
#pragma unroll
  for (int i2 = 0; i2 < 2; ++i2) {
    int d0 = wd + i2 * 16 + quad * 4;
    float4 bv = *(const float4*)&bias[d0];
    float v0 = acc[i2][0] + bv.x;
    float v1 = acc[i2][1] + bv.y;
    float v2 = acc[i2][2] + bv.z;
    float v3 = acc[i2][3] + bv.w;
    if (LAYER == 0) {
      v0 = fmaxf(v0, 0.f); v1 = fmaxf(v1, 0.f);
      v2 = fmaxf(v2, 0.f); v3 = fmaxf(v3, 0.f);
      uint2 st;
      st.x = pk2bf(v0, v1);
      st.y = pk2bf(v2, v3);
      *(uint2*)&hb_out[(size_t)n * 128 + d0] = st;
    } else {
      float4 st = make_float4(v0, v1, v2, v3);
      *(float4*)&fout[(size_t)n * 128 + d0] = st;
    }
  }
#undef LOADMETA
#undef GATHER
#undef FLUSHCUR
#undef PROCESS
#undef LOAD_FW
#undef MFMA_TILE
}

// ---------------- host ----------------
extern "C" void kernel_launch(void* const* d_in, const int* in_sizes, int n_in,
                              void* d_out, int out_size, void* d_ws, size_t ws_size,
                              hipStream_t stream) {
  const float* h0   = (const float*)d_in[0];
  const float* norm = (const float*)d_in[1];
  const float* w0   = (const float*)d_in[2];
  const float* b0   = (const float*)d_in[3];
  const float* lw0  = (const float*)d_in[4];
  const float* gw0  = (const float*)d_in[5];
  const float* w1   = (const float*)d_in[6];
  const float* b1   = (const float*)d_in[7];
  const float* lw1  = (const float*)d_in[8];
  const float* gw1  = (const float*)d_in[9];
  const int*   src  = (const int*)d_in[10];
  const int*   dst  = (const int*)d_in[11];
  const int*   rel  = (const int*)d_in[12];
  float* out = (float*)d_out;

  char* p = (char*)d_ws;
  auto alloc = [&](size_t bytes) -> void* {
    void* q = (void*)p;
    p += (bytes + 255) & ~(size_t)255;
    return q;
  };
  u16*   Wt     = (u16*)alloc((size_t)34 * 16384 * 2);
  float* gates  = (float*)alloc((size_t)NR * NN * 4);
  u16*   hbf0   = (u16*)alloc((size_t)NN * 128 * 2);
  u16*   hbf1   = (u16*)alloc((size_t)NN * 128 * 2);
  int*   counts = (int*)alloc((size_t)NP * 4);
  int*   cursor = (int*)alloc((size_t)NP * 4);
  int*   starts = (int*)alloc((size_t)(NP + 1) * 4);
  int*   bsum   = (int*)alloc((size_t)NB1 * 4);
  int*   boff   = (int*)alloc((size_t)NB1 * 4);
  u32*   esd4   = (u32*)alloc((size_t)(NE + 32) * 4);   // +32 pad: pipeline overreads
  u8*    rels   = (u8*)alloc((size_t)NE);
  float* norm_s = (float*)alloc((size_t)NE * 4);
  float* coef   = (float*)alloc((size_t)(NE + 32) * 4); // +32 pad

  // ---- sort edges by (dst, rel) — shared by both layers ----
  hipMemsetAsync(counts, 0, (size_t)NP * 4, stream);
  hist_kernel<<<NE / 256, 256, 0, stream>>>(dst, rel, counts);
  scan_partial<<<NB1, 256, 0, stream>>>(counts, bsum);
  scan_mid<<<1, 1024, 0, stream>>>(bsum, boff, starts + NP);
  scan_final<<<NB1, 256, 0, stream>>>(counts, boff, starts, cursor);
  scatter_kernel<<<NE / 256, 256, 0, stream>>>(src, dst, rel, norm, cursor,
                                               esd4, rels, norm_s);
  convert_wt<<<dim3(64, 34), 256, 0, stream>>>(w0, lw0, w1, lw1, Wt);
  hconv_kernel<<<NN * 32 / 256, 256, 0, stream>>>(h0, hbf0);

  // ---- layer 0 (relu, bf16 output) ----
  gates_kernel<<<NN / 16, 256, 0, stream>>>(hbf0, gw0, gates);
  coef_kernel<<<(NE + 255) / 256, 256, 0, stream>>>(esd4, rels, norm_s, gates, coef);
  fused_kernel<0><<<NT16, 256, 0, stream>>>(hbf0, esd4, coef, starts, Wt, b0,
                                            hbf1, nullptr);

  // ---- layer 1 (no relu, f32 output) ----
  gates_kernel<<<NN / 16, 256, 0, stream>>>(hbf1, gw1, gates);
  coef_kernel<<<(NE + 255) / 256, 256, 0, stream>>>(esd4, rels, norm_s, gates, coef);
  fused_kernel<1><<<NT16, 256, 0, stream>>>(hbf1, esd4, coef, starts,
                                            Wt + (size_t)17 * 16384, b1,
                                            nullptr, out);
}

// Round 5
// 483.306 us; speedup vs baseline: 1.6390x; 1.6390x over previous
//
#include <hip/hip_runtime.h>
#include <hip/hip_bf16.h>
#include <stdint.h>

#define NN 50000
#define NE 800000
#define NR 16
#define NP (NN * NR)                 // 800000 (dst,rel) bins
#define NB1 ((NP + 255) / 256)       // 3125
#define NTILES ((NN + 127) / 128)    // 391

typedef unsigned short u16;
typedef unsigned int u32;

typedef __bf16 bf16x8 __attribute__((ext_vector_type(8)));
typedef __bf16 bf16x2 __attribute__((ext_vector_type(2)));
typedef float f32x4 __attribute__((ext_vector_type(4)));

__device__ __forceinline__ u16 f2bf(float f) {
  u32 u = __float_as_uint(f);
  u = u + 0x7FFFu + ((u >> 16) & 1u);
  return (u16)(u >> 16);
}

__device__ __forceinline__ u32 pk2bf(float x, float y) {
#if __has_builtin(__builtin_amdgcn_cvt_pk_bf16_f32)
  bf16x2 r = __builtin_amdgcn_cvt_pk_bf16_f32(x, y);
  union { bf16x2 v; u32 u; } c;
  c.v = r;
  return c.u;
#else
  return (u32)f2bf(x) | ((u32)f2bf(y) << 16);
#endif
}

__device__ __forceinline__ float bflo(u32 w) { return __uint_as_float(w << 16); }
__device__ __forceinline__ float bfhi(u32 w) { return __uint_as_float(w & 0xFFFF0000u); }

// ---------------- edge sort by (dst, rel) — counting sort over NP bins ----------------
__global__ void hist_kernel(const int* __restrict__ dst, const int* __restrict__ rel,
                            int* __restrict__ counts) {
  int e = blockIdx.x * 256 + threadIdx.x;
  if (e < NE) atomicAdd(&counts[dst[e] * NR + rel[e]], 1);
}

__global__ void scan_partial(const int* __restrict__ counts, int* __restrict__ bsum) {
  __shared__ int buf[256];
  int t = threadIdx.x;
  int i = blockIdx.x * 256 + t;
  int v = (i < NP) ? counts[i] : 0;
  buf[t] = v;
  __syncthreads();
  for (int off = 1; off < 256; off <<= 1) {
    int x = buf[t];
    int y = (t >= off) ? buf[t - off] : 0;
    __syncthreads();
    buf[t] = x + y;
    __syncthreads();
  }
  if (t == 255) bsum[blockIdx.x] = buf[255];
}

// single block, 1024 threads, 4-serial each: scans NB1 (<=4096) block sums
__global__ void scan_mid(const int* __restrict__ bsum, int* __restrict__ boff,
                         int* __restrict__ total_out) {
  __shared__ int buf[1024];
  int t = threadIdx.x;
  int v[4];
  int sum = 0;
#pragma unroll
  for (int i = 0; i < 4; ++i) {
    int idx = t * 4 + i;
    v[i] = (idx < NB1) ? bsum[idx] : 0;
    sum += v[i];
  }
  buf[t] = sum;
  __syncthreads();
  for (int off = 1; off < 1024; off <<= 1) {
    int x = buf[t];
    int y = (t >= off) ? buf[t - off] : 0;
    __syncthreads();
    buf[t] = x + y;
    __syncthreads();
  }
  int excl = buf[t] - sum;
#pragma unroll
  for (int i = 0; i < 4; ++i) {
    int idx = t * 4 + i;
    if (idx < NB1) { boff[idx] = excl; excl += v[i]; }
  }
  if (t == 1023) *total_out = buf[1023];
}

__global__ void scan_final(const int* __restrict__ counts, const int* __restrict__ boff,
                           int* __restrict__ starts, int* __restrict__ cursor) {
  __shared__ int buf[256];
  int t = threadIdx.x;
  int i = blockIdx.x * 256 + t;
  int v = (i < NP) ? counts[i] : 0;
  buf[t] = v;
  __syncthreads();
  for (int off = 1; off < 256; off <<= 1) {
    int x = buf[t];
    int y = (t >= off) ? buf[t - off] : 0;
    __syncthreads();
    buf[t] = x + y;
    __syncthreads();
  }
  int s = boff[blockIdx.x] + buf[t] - v;
  if (i < NP) {
    starts[i] = s;
    cursor[i] = s;
  }
}

// rowidx[pos] = rel*NN + src  (indexes BOTH gates[r][n] and th[r][n][:])
__global__ void scatter_kernel(const int* __restrict__ src, const int* __restrict__ dst,
                               const int* __restrict__ rel, const float* __restrict__ norm,
                               int* __restrict__ cursor, u32* __restrict__ rowidx,
                               float* __restrict__ norm_s) {
  int e = blockIdx.x * 256 + threadIdx.x;
  if (e < NE) {
    int d = dst[e];
    int r = rel[e];
    int pos = atomicAdd(&cursor[d * NR + r], 1);
    rowidx[pos] = (u32)(r * NN + src[e]);
    norm_s[pos] = norm[e];
  }
}

// ---------------- weight convert: Wt[mat][d][k] = bf16(W[mat][k][d]) ----------------
// mats 0..15 = w0 rels, 16 = lw0, 17..32 = w1 rels, 33 = lw1
__global__ void convert_wt(const float* __restrict__ w0, const float* __restrict__ lw0,
                           const float* __restrict__ w1, const float* __restrict__ lw1,
                           u16* __restrict__ Wt) {
  int m = blockIdx.y;
  int idx = blockIdx.x * 256 + threadIdx.x; // 0..16383
  int d = idx >> 7, k = idx & 127;
  const float* s;
  if (m < 16) s = w0 + (size_t)m * 16384;
  else if (m == 16) s = lw0;
  else if (m < 33) s = w1 + (size_t)(m - 17) * 16384;
  else s = lw1;
  Wt[(size_t)m * 16384 + idx] = f2bf(s[k * 128 + d]);
}

// ---------------- h f32 -> bf16 (layer 0 input only) ----------------
__global__ void hconv_kernel(const float* __restrict__ h, u16* __restrict__ hbf) {
  int i = blockIdx.x * 256 + threadIdx.x; // float4 index
  float4 v = ((const float4*)h)[i];
  ushort4 u;
  u.x = f2bf(v.x); u.y = f2bf(v.y); u.z = f2bf(v.z); u.w = f2bf(v.w);
  ((ushort4*)hbf)[i] = u;
}

// ---------------- gate table: gates[r][n] = sigmoid(hbf[n] . gw[r]) ----------------
__global__ void gates_kernel(const u16* __restrict__ hbf, const float* __restrict__ gw,
                             float* __restrict__ gates) {
  __shared__ float hs[16 * 132];
  __shared__ float gws[16 * 132];
  int t = threadIdx.x;
  int n0 = blockIdx.x * 16;
#pragma unroll
  for (int i = 0; i < 2; ++i) {
    int f = t + 256 * i;            // 0..511
    int row = f >> 5, c4 = (f & 31) * 4;
    ushort4 u = *(const ushort4*)&hbf[(size_t)(n0 + row) * 128 + c4];
    hs[row * 132 + c4 + 0] = __uint_as_float((u32)u.x << 16);
    hs[row * 132 + c4 + 1] = __uint_as_float((u32)u.y << 16);
    hs[row * 132 + c4 + 2] = __uint_as_float((u32)u.z << 16);
    hs[row * 132 + c4 + 3] = __uint_as_float((u32)u.w << 16);
    *(float4*)&gws[row * 132 + c4] = *(const float4*)&gw[row * 128 + c4];
  }
  __syncthreads();
  int nl = t >> 4, r = t & 15;
  float s = 0.f;
#pragma unroll 8
  for (int k = 0; k < 128; ++k) s += hs[nl * 132 + k] * gws[r * 132 + k];
  gates[r * NN + n0 + nl] = 1.f / (1.f + __expf(-s));
}

// ---------------- per-edge coefficient: coef[e] = gate[rowidx] * norm ----------------
// rowidx = rel*NN+src indexes gates[r][n] directly. gates (3.2 MB) is L2-resident.
__global__ void coef_kernel(const u32* __restrict__ rowidx,
                            const float* __restrict__ norm_s,
                            const float* __restrict__ gates, float* __restrict__ coef) {
  int e = blockIdx.x * 256 + threadIdx.x;
  if (e < NE) coef[e] = gates[rowidx[e]] * norm_s[e];
}

// ---------------- transform: th[m][n][:] = hbf @ W_m for m = 0..16 ----------------
// Dense streaming GEMM, grid (391, 17). Fragment mapping / staging copied verbatim
// from the round-0 VERIFIED biggemm (single mat, K=128, one phase). Write-bound:
// 217.6 MB bf16 out per layer at streaming rate.
__global__ __launch_bounds__(256, 2)
void transform_kernel(const u16* __restrict__ hbf, const u16* __restrict__ Wtbase,
                      u16* __restrict__ th) {
  __shared__ u16 As[128 * 136];     // node rows tile, pad +8
  __shared__ u16 Ws[128 * 136];     // W rows = d
  int t = threadIdx.x;
  int n0 = blockIdx.x * 128;
  int m = blockIdx.y;               // 0..16 (16 = self loop)
  const u16* wmat = Wtbase + (size_t)m * 16384;
  int wave = t >> 6, lane = t & 63;
  int wd = (wave & 1) * 64, wn = (wave >> 1) * 64;
  int mrow = lane & 15, quad = lane >> 4;

#pragma unroll
  for (int i = 0; i < 8; ++i) {
    int u8i = t + 256 * i;          // 0..2047 uint4 slots = 128 rows x 16
    int row = u8i >> 4, c8 = (u8i & 15) * 8;
    int n = n0 + row;
    int nc = n < NN ? n : NN - 1;   // clamp; garbage rows never stored
    *(uint4*)&Ws[row * 136 + c8] = *(const uint4*)&wmat[row * 128 + c8];
    *(uint4*)&As[row * 136 + c8] = *(const uint4*)&hbf[(size_t)nc * 128 + c8];
  }
  __syncthreads();

  f32x4 acc[4][4];
#pragma unroll
  for (int i = 0; i < 4; ++i)
#pragma unroll
    for (int j = 0; j < 4; ++j) acc[i][j] = (f32x4){0.f, 0.f, 0.f, 0.f};

#pragma unroll
  for (int kk = 0; kk < 4; ++kk) {
    int k0 = kk * 32 + quad * 8;
    bf16x8 fa[4], fb[4];
#pragma unroll
    for (int i2 = 0; i2 < 4; ++i2)
      fa[i2] = *(const bf16x8*)&Ws[(wd + i2 * 16 + mrow) * 136 + k0];
#pragma unroll
    for (int j2 = 0; j2 < 4; ++j2)
      fb[j2] = *(const bf16x8*)&As[(wn + j2 * 16 + mrow) * 136 + k0];
#pragma unroll
    for (int i2 = 0; i2 < 4; ++i2)
#pragma unroll
      for (int j2 = 0; j2 < 4; ++j2)
        acc[i2][j2] = __builtin_amdgcn_mfma_f32_16x16x32_bf16(fa[i2], fb[j2],
                                                              acc[i2][j2], 0, 0, 0);
  }

  // epilogue: lane owns node = n0+wn+j*16+mrow, d = wd+i*16+quad*4 .. +3
#pragma unroll
  for (int j = 0; j < 4; ++j) {
    int n = n0 + wn + j * 16 + mrow;
    if (n < NN) {
#pragma unroll
      for (int i = 0; i < 4; ++i) {
        int d0 = wd + i * 16 + quad * 4;
        uint2 st;
        st.x = pk2bf(acc[i][j][0], acc[i][j][1]);
        st.y = pk2bf(acc[i][j][2], acc[i][j][3]);
        *(uint2*)&th[((size_t)m * NN + n) * 128 + d0] = st;
      }
    }
  }
}

// ---------------- gatheradd: out[v] = sum coef*th[rowidx] + th_self[v] + b ----------
// Round-0 aggregation geometry (12500 blocks x 4 waves, 1 node/wave, batch-8 gathers)
// but with NO per-rel flush walk, NO gate gather, NO agg intermediate: one f32
// accumulator pair per lane across ALL the node's edges, epilogue adds self+bias.
// Masked batch-8: every edge takes the batched (one-wait-per-8) path; invalid slots
// clamp the index (valid memory) and zero the coefficient.
template <int LAYER>
__global__ __launch_bounds__(256)
void gatheradd_kernel(const u16* __restrict__ th, const u32* __restrict__ rowidx,
                      const float* __restrict__ coef, const int* __restrict__ starts,
                      const float* __restrict__ bias,
                      u16* __restrict__ hb_out, float* __restrict__ fout) {
  const u32* th32 = (const u32*)th;
  int wave = threadIdx.x >> 6;
  u32 lane = (u32)(threadIdx.x & 63);
  int v = blockIdx.x * 4 + wave;    // NN = 12500*4 -> always < NN
  int s = starts[v * NR];
  int e = starts[v * NR + NR];      // starts[NP] sentinel = NE for v = NN-1
  float a0 = 0.f, a1 = 0.f;
  for (int j = s; j < e; j += 8) {
    u32 ri[8];
    float cf[8];
#pragma unroll
    for (int i = 0; i < 8; ++i) {
      int ii = (j + i < e) ? (j + i) : (e - 1);
      ri[i] = rowidx[ii];
      cf[i] = (j + i < e) ? coef[ii] : 0.f;
    }
    u32 w[8];
#pragma unroll
    for (int i = 0; i < 8; ++i) w[i] = th32[ri[i] * 64u + lane];
#pragma unroll
    for (int i = 0; i < 8; ++i) {
      a0 = fmaf(cf[i], bflo(w[i]), a0);
      a1 = fmaf(cf[i], bfhi(w[i]), a1);
    }
  }
  // self-loop (th mat 16) + bias
  u32 ts = th32[((u32)(16 * NN) + (u32)v) * 64u + lane];
  float2 bv = *(const float2*)&bias[lane * 2u];
  a0 += bflo(ts) + bv.x;
  a1 += bfhi(ts) + bv.y;
  if (LAYER == 0) {
    a0 = fmaxf(a0, 0.f);
    a1 = fmaxf(a1, 0.f);
    ((u32*)hb_out)[(size_t)v * 64 + lane] = pk2bf(a0, a1);
  } else {
    *(float2*)&fout[(size_t)v * 128 + lane * 2u] = make_float2(a0, a1);
  }
}

// ---------------- host ----------------
extern "C" void kernel_launch(void* const* d_in, const int* in_sizes, int n_in,
                              void* d_out, int out_size, void* d_ws, size_t ws_size,
                              hipStream_t stream) {
  const float* h0   = (const float*)d_in[0];
  const float* norm = (const float*)d_in[1];
  const float* w0   = (const float*)d_in[2];
  const float* b0   = (const float*)d_in[3];
  const float* lw0  = (const float*)d_in[4];
  const float* gw0  = (const float*)d_in[5];
  const float* w1   = (const float*)d_in[6];
  const float* b1   = (const float*)d_in[7];
  const float* lw1  = (const float*)d_in[8];
  const float* gw1  = (const float*)d_in[9];
  const int*   src  = (const int*)d_in[10];
  const int*   dst  = (const int*)d_in[11];
  const int*   rel  = (const int*)d_in[12];
  float* out = (float*)d_out;

  char* p = (char*)d_ws;
  auto alloc = [&](size_t bytes) -> void* {
    void* q = (void*)p;
    p += (bytes + 255) & ~(size_t)255;
    return q;
  };
  u16*   Wt     = (u16*)alloc((size_t)34 * 16384 * 2);        // 1.1 MB
  float* gates  = (float*)alloc((size_t)NR * NN * 4);         // 3.2 MB
  u16*   hbf    = (u16*)alloc((size_t)NN * 128 * 2);          // 12.8 MB (h0 then h1)
  int*   counts = (int*)alloc((size_t)NP * 4);                // 3.2 MB
  int*   cursor = (int*)alloc((size_t)NP * 4);                // 3.2 MB
  int*   starts = (int*)alloc((size_t)(NP + 1) * 4);          // 3.2 MB
  int*   bsum   = (int*)alloc((size_t)NB1 * 4);
  int*   boff   = (int*)alloc((size_t)NB1 * 4);
  u32*   rowidx = (u32*)alloc((size_t)NE * 4);                // 3.2 MB
  u16*   th     = (u16*)alloc((size_t)17 * NN * 128 * 2);     // 217.6 MB
  // aliases over dead buffers (keeps total footprint <= round-0's proven 251 MB):
  float* norm_s = (float*)counts;   // counts dead after scan_final; written by scatter
  float* coef   = (float*)cursor;   // cursor dead after scatter; written by coef_kernel

  // ---- sort edges by (dst, rel) — shared by both layers ----
  hipMemsetAsync(counts, 0, (size_t)NP * 4, stream);
  hist_kernel<<<NE / 256, 256, 0, stream>>>(dst, rel, counts);
  scan_partial<<<NB1, 256, 0, stream>>>(counts, bsum);
  scan_mid<<<1, 1024, 0, stream>>>(bsum, boff, starts + NP);
  scan_final<<<NB1, 256, 0, stream>>>(counts, boff, starts, cursor);
  scatter_kernel<<<NE / 256, 256, 0, stream>>>(src, dst, rel, norm, cursor,
                                               rowidx, norm_s);
  convert_wt<<<dim3(64, 34), 256, 0, stream>>>(w0, lw0, w1, lw1, Wt);
  hconv_kernel<<<NN * 32 / 256, 256, 0, stream>>>(h0, hbf);

  // ---- layer 0 (relu, bf16 output back into hbf) ----
  gates_kernel<<<NN / 16, 256, 0, stream>>>(hbf, gw0, gates);
  coef_kernel<<<(NE + 255) / 256, 256, 0, stream>>>(rowidx, norm_s, gates, coef);
  transform_kernel<<<dim3(NTILES, 17), 256, 0, stream>>>(hbf, Wt, th);
  gatheradd_kernel<0><<<NN / 4, 256, 0, stream>>>(th, rowidx, coef, starts, b0,
                                                  hbf, nullptr);

  // ---- layer 1 (no relu, f32 output) ----
  gates_kernel<<<NN / 16, 256, 0, stream>>>(hbf, gw1, gates);
  coef_kernel<<<(NE + 255) / 256, 256, 0, stream>>>(rowidx, norm_s, gates, coef);
  transform_kernel<<<dim3(NTILES, 17), 256, 0, stream>>>(hbf, Wt + (size_t)17 * 16384,
                                                         th);
  gatheradd_kernel<1><<<NN / 4, 256, 0, stream>>>(th, rowidx, coef, starts, b1,
                                                  nullptr, out);
}